// Round 1
// baseline (1674.367 us; speedup 1.0000x reference)
//
#include <hip/hip_runtime.h>
#include <hip/hip_bf16.h>
#include <cstdint>

#define B_TOK 16384
#define HDIM  1024
#define HGATE 512
#define NPATH 8
#define THRV  0.1f

typedef __bf16 bf16x8 __attribute__((ext_vector_type(8)));
typedef float  f32x4  __attribute__((ext_vector_type(4)));
typedef unsigned short u16;

__device__ __forceinline__ u16 f2bf(float f) {
    uint32_t u = __float_as_uint(f);
    u += 0x7fff + ((u >> 16) & 1);   // RNE
    return (u16)(u >> 16);
}
__device__ __forceinline__ float silu_f(float a) {
    return a / (1.0f + expf(-a));
}
__device__ __forceinline__ f32x4 mfma_bf16(bf16x8 a, bf16x8 b, f32x4 c) {
    return __builtin_amdgcn_mfma_f32_16x16x32_bf16(a, b, c, 0, 0, 0);
}

// ---------------- x -> bf16 ----------------
__global__ void k_convert_x(const float* __restrict__ x, u16* __restrict__ xb) {
    int i = (blockIdx.x * 256 + threadIdx.x) * 4;
    float4 v = *(const float4*)(x + i);
    uint2 o;
    o.x = (uint32_t)f2bf(v.x) | ((uint32_t)f2bf(v.y) << 16);
    o.y = (uint32_t)f2bf(v.z) | ((uint32_t)f2bf(v.w) << 16);
    *(uint2*)(xb + i) = o;
}

// ---------------- W (P,H,H) fp32 -> WT (P,H,H) bf16, WT[p][d][h]=W[p][h][d] ----------------
__global__ void k_transpose_bf16(const float* __restrict__ W, u16* __restrict__ WT) {
    __shared__ float tile[32][33];
    int p = blockIdx.z;
    const float* Wp = W + (size_t)p * HDIM * HDIM;
    u16* WTp = WT + (size_t)p * HDIM * HDIM;
    int d0 = blockIdx.x * 32, h0 = blockIdx.y * 32;
    int tx = threadIdx.x, ty = threadIdx.y;  // (32,8)
    #pragma unroll
    for (int rr = 0; rr < 4; rr++) {
        int r = ty + rr * 8;
        tile[r][tx] = Wp[(size_t)(h0 + r) * HDIM + d0 + tx];
    }
    __syncthreads();
    #pragma unroll
    for (int rr = 0; rr < 4; rr++) {
        int r = ty + rr * 8;
        WTp[(size_t)(d0 + r) * HDIM + h0 + tx] = f2bf(tile[tx][r]);
    }
}

// ---------------- fp32 GEMM: h = silu(x @ W1 + b1), M=B_TOK N=512 K=1024 ----------------
__global__ __launch_bounds__(256) void k_gemm_gate(const float* __restrict__ X,
                                                   const float* __restrict__ W1,
                                                   const float* __restrict__ b1,
                                                   float* __restrict__ Hout) {
    __shared__ float As[16 * 64];
    __shared__ float Bs[16 * 64];
    int t = threadIdx.x;
    int tx = t & 15, ty = t >> 4;
    int n0 = blockIdx.x * 64, m0 = blockIdx.y * 64;
    float acc[4][4] = {};
    for (int kt = 0; kt < HDIM / 16; kt++) {
        __syncthreads();
        {
            int m = t >> 2, kq = (t & 3) * 4;
            float4 v = *(const float4*)(X + (size_t)(m0 + m) * HDIM + kt * 16 + kq);
            As[(kq + 0) * 64 + m] = v.x;
            As[(kq + 1) * 64 + m] = v.y;
            As[(kq + 2) * 64 + m] = v.z;
            As[(kq + 3) * 64 + m] = v.w;
        }
        {
            int r = t >> 4, cq = (t & 15) * 4;
            *(float4*)(Bs + r * 64 + cq) =
                *(const float4*)(W1 + (size_t)(kt * 16 + r) * HGATE + n0 + cq);
        }
        __syncthreads();
        #pragma unroll
        for (int kk = 0; kk < 16; kk++) {
            float4 av4 = *(float4*)(As + kk * 64 + ty * 4);
            float4 bv4 = *(float4*)(Bs + kk * 64 + tx * 4);
            float a[4] = {av4.x, av4.y, av4.z, av4.w};
            float b[4] = {bv4.x, bv4.y, bv4.z, bv4.w};
            #pragma unroll
            for (int i = 0; i < 4; i++)
                #pragma unroll
                for (int j = 0; j < 4; j++) acc[i][j] += a[i] * b[j];
        }
    }
    #pragma unroll
    for (int i = 0; i < 4; i++) {
        int row = m0 + ty * 4 + i;
        float4 o;
        float* po = (float*)&o;
        #pragma unroll
        for (int j = 0; j < 4; j++) {
            int col = n0 + tx * 4 + j;
            po[j] = silu_f(acc[i][j] + b1[col]);
        }
        *(float4*)(Hout + (size_t)row * HGATE + n0 + tx * 4) = o;
    }
}

// ---------------- per-token: logits -> softmax -> top2/threshold ----------------
__global__ __launch_bounds__(256) void k_gate_topk(const float* __restrict__ Hin,
                                                   const float* __restrict__ W2,
                                                   const float* __restrict__ b2,
                                                   float* __restrict__ gate_out,
                                                   float* __restrict__ wnorm,
                                                   float* __restrict__ flagb) {
    __shared__ float w2t[NPATH * HGATE];
    int t = threadIdx.x;
    #pragma unroll
    for (int j = 0; j < 16; j++) {
        int i = t + j * 256;
        int k = i >> 3, p = i & 7;
        w2t[p * HGATE + k] = W2[i];
    }
    __syncthreads();
    int wave = t >> 6, lane = t & 63;
    int token = blockIdx.x * 4 + wave;
    const float* hrow = Hin + (size_t)token * HGATE;
    float hv[8];
    {
        float4 h0 = *(const float4*)(hrow + lane * 8);
        float4 h1 = *(const float4*)(hrow + lane * 8 + 4);
        hv[0] = h0.x; hv[1] = h0.y; hv[2] = h0.z; hv[3] = h0.w;
        hv[4] = h1.x; hv[5] = h1.y; hv[6] = h1.z; hv[7] = h1.w;
    }
    float logit[8];
    #pragma unroll
    for (int p = 0; p < 8; p++) {
        float s = 0.0f;
        #pragma unroll
        for (int kk = 0; kk < 8; kk++) s += hv[kk] * w2t[p * HGATE + lane * 8 + kk];
        #pragma unroll
        for (int off = 32; off >= 1; off >>= 1) s += __shfl_xor(s, off);
        logit[p] = s + b2[p];
    }
    float mx = logit[0];
    #pragma unroll
    for (int p = 1; p < 8; p++) mx = fmaxf(mx, logit[p]);
    float pr[8], sum = 0.0f;
    #pragma unroll
    for (int p = 0; p < 8; p++) { pr[p] = expf(logit[p] - mx); sum += pr[p]; }
    float inv = 1.0f / sum;
    #pragma unroll
    for (int p = 0; p < 8; p++) pr[p] *= inv;
    // top-2, ties -> lowest index (matches lax.top_k)
    int i0 = 0; float v0 = pr[0];
    #pragma unroll
    for (int p = 1; p < 8; p++) { if (pr[p] > v0) { v0 = pr[p]; i0 = p; } }
    int i1 = -1; float v1 = -1.0f;
    #pragma unroll
    for (int p = 0; p < 8; p++) { if (p != i0 && pr[p] > v1) { v1 = pr[p]; i1 = p; } }
    float w0 = (v0 > THRV) ? v0 : 0.0f;
    float w1 = (v1 > THRV) ? v1 : 0.0f;
    float total = w0 + w1;
    int fired = (total > 0.0f) ? 1 : 0;
    float invden = fired ? (1.0f / total) : 1.0f;
    if (lane < 8) {
        float prl = pr[0];
        #pragma unroll
        for (int p = 1; p < 8; p++) prl = (lane == p) ? pr[p] : prl;
        float wl = 0.0f;
        if (lane == i0) wl = w0 * invden;
        if (lane == i1) wl = w1 * invden;
        gate_out[(size_t)token * 8 + lane] = prl;
        wnorm[(size_t)token * 8 + lane] = wl;
        if (lane == 0) flagb[token] = fired ? 1.0f : 0.0f;
    }
}

// ---------------- bf16 MFMA GEMM (A: MxK row-major, BT: NxK row-major), 128x128 tile ----
// MODE 1: hid = bf16(silu(A@B + bias));  MODE 2: combined (+)= wnorm[:,p] * (A@B)
template <int MODE>
__global__ __launch_bounds__(256) void k_gemm_path(const u16* __restrict__ A,
                                                   const u16* __restrict__ BT,
                                                   const float* __restrict__ bias,
                                                   u16* __restrict__ hid,
                                                   float* __restrict__ combined,
                                                   const float* __restrict__ wnorm,
                                                   int pidx, int initflag) {
    __shared__ __align__(16) u16 smem[16384];  // 32KB
    u16* lA = smem;
    u16* lB = smem + 4096;
    int t = threadIdx.x;
    int n0 = blockIdx.x * 128, m0 = blockIdx.y * 128;
    int wave = t >> 6, lane = t & 63;
    int quad = lane >> 4, l16 = lane & 15;
    int wr = (wave >> 1) * 64, wc = (wave & 1) * 64;
    f32x4 acc[4][4] = {};
    union UV { uint4 u; bf16x8 v; };

    for (int kt = 0; kt < HDIM / 32; kt++) {
        __syncthreads();
        #pragma unroll
        for (int s = 0; s < 2; s++) {
            int c = t + s * 256;
            int row = c >> 2, c8 = (c & 3) * 8;
            *(uint4*)(lA + c * 8) = *(const uint4*)(A + (size_t)(m0 + row) * HDIM + kt * 32 + c8);
            *(uint4*)(lB + c * 8) = *(const uint4*)(BT + (size_t)(n0 + row) * HDIM + kt * 32 + c8);
        }
        __syncthreads();
        bf16x8 av[4], bv[4];
        #pragma unroll
        for (int i = 0; i < 4; i++) {
            UV ua; ua.u = *(uint4*)(lA + ((wr + i * 16 + l16) * 32 + quad * 8));
            av[i] = ua.v;
            UV ub; ub.u = *(uint4*)(lB + ((wc + i * 16 + l16) * 32 + quad * 8));
            bv[i] = ub.v;
        }
        #pragma unroll
        for (int i = 0; i < 4; i++)
            #pragma unroll
            for (int j = 0; j < 4; j++)
                acc[i][j] = mfma_bf16(av[i], bv[j], acc[i][j]);
    }
    __syncthreads();

    if (MODE == 1) {
        #pragma unroll
        for (int j = 0; j < 4; j++) {
            float bj = bias[n0 + wc + j * 16 + l16];
            #pragma unroll
            for (int i = 0; i < 4; i++)
                #pragma unroll
                for (int r = 0; r < 4; r++) {
                    int rrow = wr + i * 16 + quad * 4 + r;
                    smem[rrow * 128 + wc + j * 16 + l16] = f2bf(silu_f(acc[i][j][r] + bj));
                }
        }
        __syncthreads();
        #pragma unroll
        for (int it = 0; it < 8; it++) {
            int c = t + it * 256;
            int row = c >> 4, c8 = (c & 15) * 8;
            *(uint4*)(hid + (size_t)(m0 + row) * HDIM + n0 + c8) = *(uint4*)(smem + c * 8);
        }
    } else {
        float* smf = (float*)smem;  // 64x128 fp32 per half
        #pragma unroll
        for (int half = 0; half < 2; half++) {
            if ((wave >> 1) == half) {
                #pragma unroll
                for (int i = 0; i < 4; i++)
                    #pragma unroll
                    for (int r = 0; r < 4; r++) {
                        int rrow = i * 16 + quad * 4 + r;
                        float wn = wnorm[(size_t)(m0 + half * 64 + rrow) * NPATH + pidx];
                        #pragma unroll
                        for (int j = 0; j < 4; j++)
                            smf[rrow * 128 + wc + j * 16 + l16] = wn * acc[i][j][r];
                    }
            }
            __syncthreads();
            #pragma unroll
            for (int it = 0; it < 8; it++) {
                int c = t + it * 256;
                int row = c >> 5, c4 = (c & 31) * 4;
                float* gp = combined + (size_t)(m0 + half * 64 + row) * HDIM + n0 + c4;
                float4 v = *(float4*)(smf + c * 4);
                if (!initflag) {
                    float4 g = *(float4*)gp;
                    v.x += g.x; v.y += g.y; v.z += g.z; v.w += g.w;
                }
                *(float4*)gp = v;
            }
            __syncthreads();
        }
    }
}

// ---------------- final blend ----------------
__global__ void k_blend(const float* __restrict__ x, const float* __restrict__ combined,
                        const float* __restrict__ flagb, const float* __restrict__ blend,
                        float* __restrict__ out) {
    int i = (blockIdx.x * 256 + threadIdx.x) * 4;
    int b = i >> 10;
    float alpha = 1.0f / (1.0f + expf(-blend[0]));
    float4 xv = *(const float4*)(x + i);
    float4 o;
    if (flagb[b] > 0.0f) {
        float4 cv = *(const float4*)(combined + i);
        float be = 1.0f - alpha;
        o.x = alpha * cv.x + be * xv.x;
        o.y = alpha * cv.y + be * xv.y;
        o.z = alpha * cv.z + be * xv.z;
        o.w = alpha * cv.w + be * xv.w;
    } else {
        o = xv;
    }
    *(float4*)(out + i) = o;
}

extern "C" void kernel_launch(void* const* d_in, const int* in_sizes, int n_in,
                              void* d_out, int out_size, void* d_ws, size_t ws_size,
                              hipStream_t stream) {
    const float* x   = (const float*)d_in[0];
    const float* gw1 = (const float*)d_in[1];
    const float* gb1 = (const float*)d_in[2];
    const float* gw2 = (const float*)d_in[3];
    const float* gb2 = (const float*)d_in[4];
    const float* pw  = (const float*)d_in[5];
    const float* pb  = (const float*)d_in[6];
    const float* prw = (const float*)d_in[7];
    const float* blend = (const float*)d_in[8];
    float* out = (float*)d_out;
    float* gate_out = out + (size_t)B_TOK * HDIM;

    char* w = (char*)d_ws;
    size_t o = 0;
    u16* xb      = (u16*)(w + o);   o += (size_t)B_TOK * HDIM * 2;
    u16* pathWT  = (u16*)(w + o);   o += (size_t)NPATH * HDIM * HDIM * 2;
    u16* projWT  = (u16*)(w + o);   o += (size_t)NPATH * HDIM * HDIM * 2;
    float* hbuf  = (float*)(w + o); o += (size_t)B_TOK * HGATE * 4;
    u16* hid     = (u16*)(w + o);   o += (size_t)B_TOK * HDIM * 2;
    float* combined = (float*)(w + o); o += (size_t)B_TOK * HDIM * 4;
    float* wnorm = (float*)(w + o); o += (size_t)B_TOK * NPATH * 4;
    float* flagb = (float*)(w + o); o += (size_t)B_TOK * 4;

    k_convert_x<<<dim3((B_TOK * HDIM) / 1024), dim3(256), 0, stream>>>(x, xb);
    k_transpose_bf16<<<dim3(32, 32, 8), dim3(32, 8), 0, stream>>>(pw, pathWT);
    k_transpose_bf16<<<dim3(32, 32, 8), dim3(32, 8), 0, stream>>>(prw, projWT);
    k_gemm_gate<<<dim3(HGATE / 64, B_TOK / 64), dim3(256), 0, stream>>>(x, gw1, gb1, hbuf);
    k_gate_topk<<<dim3(B_TOK / 4), dim3(256), 0, stream>>>(hbuf, gw2, gb2, gate_out, wnorm, flagb);
    for (int p = 0; p < NPATH; p++) {
        k_gemm_path<1><<<dim3(HDIM / 128, B_TOK / 128), dim3(256), 0, stream>>>(
            xb, pathWT + (size_t)p * HDIM * HDIM, pb + (size_t)p * HDIM,
            hid, nullptr, nullptr, p, 0);
        k_gemm_path<2><<<dim3(HDIM / 128, B_TOK / 128), dim3(256), 0, stream>>>(
            hid, projWT + (size_t)p * HDIM * HDIM, nullptr,
            nullptr, combined, wnorm, p, (p == 0) ? 1 : 0);
    }
    k_blend<<<dim3((B_TOK * HDIM) / 1024), dim3(256), 0, stream>>>(x, combined, flagb, blend, out);
}

// Round 2
// 795.220 us; speedup vs baseline: 2.1055x; 2.1055x over previous
//
#include <hip/hip_runtime.h>
#include <hip/hip_bf16.h>
#include <cstdint>

#define B_TOK 16384
#define HDIM  1024
#define HGATE 512
#define NPATH 8
#define THRV  0.1f
#define MAXROWS (2 * B_TOK + NPATH * 128)   // padded compact rows bound

typedef __bf16 bf16x8 __attribute__((ext_vector_type(8)));
typedef float  f32x4  __attribute__((ext_vector_type(4)));
typedef unsigned short u16;

__device__ __forceinline__ u16 f2bf(float f) {
    uint32_t u = __float_as_uint(f);
    u += 0x7fff + ((u >> 16) & 1);   // RNE
    return (u16)(u >> 16);
}
__device__ __forceinline__ float bf2f(u16 v) {
    return __uint_as_float((uint32_t)v << 16);
}
__device__ __forceinline__ float silu_f(float a) {
    return a / (1.0f + expf(-a));
}
__device__ __forceinline__ f32x4 mfma_bf16(bf16x8 a, bf16x8 b, f32x4 c) {
    return __builtin_amdgcn_mfma_f32_16x16x32_bf16(a, b, c, 0, 0, 0);
}

// ---------------- x -> bf16 ----------------
__global__ void k_convert_x(const float* __restrict__ x, u16* __restrict__ xb) {
    int i = (blockIdx.x * 256 + threadIdx.x) * 4;
    float4 v = *(const float4*)(x + i);
    uint2 o;
    o.x = (uint32_t)f2bf(v.x) | ((uint32_t)f2bf(v.y) << 16);
    o.y = (uint32_t)f2bf(v.z) | ((uint32_t)f2bf(v.w) << 16);
    *(uint2*)(xb + i) = o;
}

// ---------------- W (P,H,H) fp32 -> WT (P,H,H) bf16, WT[p][d][h]=W[p][h][d] ----------------
__global__ void k_transpose_bf16(const float* __restrict__ W, u16* __restrict__ WT) {
    __shared__ float tile[32][33];
    int p = blockIdx.z;
    const float* Wp = W + (size_t)p * HDIM * HDIM;
    u16* WTp = WT + (size_t)p * HDIM * HDIM;
    int d0 = blockIdx.x * 32, h0 = blockIdx.y * 32;
    int tx = threadIdx.x, ty = threadIdx.y;  // (32,8)
    #pragma unroll
    for (int rr = 0; rr < 4; rr++) {
        int r = ty + rr * 8;
        tile[r][tx] = Wp[(size_t)(h0 + r) * HDIM + d0 + tx];
    }
    __syncthreads();
    #pragma unroll
    for (int rr = 0; rr < 4; rr++) {
        int r = ty + rr * 8;
        WTp[(size_t)(d0 + r) * HDIM + h0 + tx] = f2bf(tile[tx][r]);
    }
}

// ---------------- fp32 GEMM: h = silu(x @ W1 + b1), M=B_TOK N=512 K=1024 ----------------
// LDS row stride 68 floats (16B-aligned, breaks 4-way bank conflict of stride 64)
__global__ __launch_bounds__(256) void k_gemm_gate(const float* __restrict__ X,
                                                   const float* __restrict__ W1,
                                                   const float* __restrict__ b1,
                                                   float* __restrict__ Hout) {
    __shared__ float As[16 * 68];
    __shared__ float Bs[16 * 68];
    int t = threadIdx.x;
    int tx = t & 15, ty = t >> 4;
    int n0 = blockIdx.x * 64, m0 = blockIdx.y * 64;
    float acc[4][4] = {};
    for (int kt = 0; kt < HDIM / 16; kt++) {
        __syncthreads();
        {
            int m = t >> 2, kq = (t & 3) * 4;
            float4 v = *(const float4*)(X + (size_t)(m0 + m) * HDIM + kt * 16 + kq);
            As[(kq + 0) * 68 + m] = v.x;
            As[(kq + 1) * 68 + m] = v.y;
            As[(kq + 2) * 68 + m] = v.z;
            As[(kq + 3) * 68 + m] = v.w;
        }
        {
            int r = t >> 4, cq = (t & 15) * 4;
            *(float4*)(Bs + r * 68 + cq) =
                *(const float4*)(W1 + (size_t)(kt * 16 + r) * HGATE + n0 + cq);
        }
        __syncthreads();
        #pragma unroll
        for (int kk = 0; kk < 16; kk++) {
            float4 av4 = *(float4*)(As + kk * 68 + ty * 4);
            float4 bv4 = *(float4*)(Bs + kk * 68 + tx * 4);
            float a[4] = {av4.x, av4.y, av4.z, av4.w};
            float b[4] = {bv4.x, bv4.y, bv4.z, bv4.w};
            #pragma unroll
            for (int i = 0; i < 4; i++)
                #pragma unroll
                for (int j = 0; j < 4; j++) acc[i][j] += a[i] * b[j];
        }
    }
    #pragma unroll
    for (int i = 0; i < 4; i++) {
        int row = m0 + ty * 4 + i;
        float4 o;
        float* po = (float*)&o;
        #pragma unroll
        for (int j = 0; j < 4; j++) {
            int col = n0 + tx * 4 + j;
            po[j] = silu_f(acc[i][j] + b1[col]);
        }
        *(float4*)(Hout + (size_t)row * HGATE + n0 + tx * 4) = o;
    }
}

// ---------------- per-token: logits -> softmax -> top2/threshold + list build --------
// block = 256 thr = 4 waves; each wave handles 16 tokens sequentially (64/token-block)
__global__ __launch_bounds__(256) void k_gate_topk(const float* __restrict__ Hin,
                                                   const float* __restrict__ W2,
                                                   const float* __restrict__ b2,
                                                   float* __restrict__ gate_out,
                                                   float* __restrict__ wnorm,
                                                   int* __restrict__ counts,
                                                   int* __restrict__ tokens,
                                                   uint32_t* __restrict__ slots) {
    __shared__ float w2t[NPATH * HGATE];
    __shared__ int cnt[NPATH];
    __shared__ int baseS[NPATH];
    __shared__ unsigned short tloc[NPATH][64];
    __shared__ uint32_t sloc[64][2];
    int t = threadIdx.x;
    #pragma unroll
    for (int j = 0; j < 16; j++) {
        int i = t + j * 256;
        w2t[(i & 7) * HGATE + (i >> 3)] = W2[i];
    }
    if (t < NPATH) cnt[t] = 0;
    __syncthreads();
    int wave = t >> 6, lane = t & 63;
    #pragma unroll 1
    for (int it = 0; it < 16; it++) {
        int tl = wave * 16 + it;
        int token = blockIdx.x * 64 + tl;
        const float* hrow = Hin + (size_t)token * HGATE;
        float hv[8];
        {
            float4 h0 = *(const float4*)(hrow + lane * 8);
            float4 h1 = *(const float4*)(hrow + lane * 8 + 4);
            hv[0] = h0.x; hv[1] = h0.y; hv[2] = h0.z; hv[3] = h0.w;
            hv[4] = h1.x; hv[5] = h1.y; hv[6] = h1.z; hv[7] = h1.w;
        }
        float logit[8];
        #pragma unroll
        for (int p = 0; p < 8; p++) {
            float s = 0.0f;
            #pragma unroll
            for (int kk = 0; kk < 8; kk++) s += hv[kk] * w2t[p * HGATE + lane * 8 + kk];
            #pragma unroll
            for (int off = 32; off >= 1; off >>= 1) s += __shfl_xor(s, off);
            logit[p] = s + b2[p];
        }
        float mx = logit[0];
        #pragma unroll
        for (int p = 1; p < 8; p++) mx = fmaxf(mx, logit[p]);
        float pr[8], sum = 0.0f;
        #pragma unroll
        for (int p = 0; p < 8; p++) { pr[p] = expf(logit[p] - mx); sum += pr[p]; }
        float inv = 1.0f / sum;
        #pragma unroll
        for (int p = 0; p < 8; p++) pr[p] *= inv;
        // top-2, ties -> lowest index (matches lax.top_k)
        int i0 = 0; float v0 = pr[0];
        #pragma unroll
        for (int p = 1; p < 8; p++) { if (pr[p] > v0) { v0 = pr[p]; i0 = p; } }
        int i1 = -1; float v1 = -1.0f;
        #pragma unroll
        for (int p = 0; p < 8; p++) { if (p != i0 && pr[p] > v1) { v1 = pr[p]; i1 = p; } }
        float w0 = (v0 > THRV) ? v0 : 0.0f;
        float w1 = (v1 > THRV) ? v1 : 0.0f;
        float total = w0 + w1;
        float invden = (total > 0.0f) ? (1.0f / total) : 1.0f;
        if (lane < 8) {
            float prl = pr[0];
            #pragma unroll
            for (int p = 1; p < 8; p++) prl = (lane == p) ? pr[p] : prl;
            float wl = 0.0f;
            if (lane == i0) wl = w0 * invden;
            if (lane == i1) wl = w1 * invden;
            gate_out[(size_t)token * 8 + lane] = prl;
            wnorm[(size_t)token * 8 + lane] = wl;
        }
        if (lane == 0) {
            uint32_t e0 = 0xFFFFFFFFu, e1 = 0xFFFFFFFFu;
            if (w0 > 0.0f) {
                int j0 = atomicAdd(&cnt[i0], 1);
                tloc[i0][j0] = (unsigned short)tl;
                e0 = ((uint32_t)i0 << 16) | (uint32_t)j0;
            }
            if (w1 > 0.0f) {
                int j1 = atomicAdd(&cnt[i1], 1);
                tloc[i1][j1] = (unsigned short)tl;
                e1 = ((uint32_t)i1 << 16) | (uint32_t)j1;
            }
            sloc[tl][0] = e0; sloc[tl][1] = e1;
        }
    }
    __syncthreads();
    if (t < NPATH) baseS[t] = atomicAdd(&counts[t], cnt[t]);
    __syncthreads();
    for (int p = 0; p < NPATH; p++) {
        int n = cnt[p], b = baseS[p];
        for (int j = t; j < n; j += 256)
            tokens[p * B_TOK + b + j] = blockIdx.x * 64 + tloc[p][j];
    }
    if (t < 64) {
        #pragma unroll
        for (int s = 0; s < 2; s++) {
            uint32_t e = sloc[t][s];
            if (e != 0xFFFFFFFFu) {
                int p = e >> 16;
                int j = (int)(e & 0xFFFFu) + baseS[p];
                e = ((uint32_t)p << 16) | (uint32_t)j;
            }
            slots[(size_t)(blockIdx.x * 64 + t) * 2 + s] = e;
        }
    }
}

// ---------------- padded prefix offsets ----------------
__global__ void k_prefix(const int* __restrict__ counts, int* __restrict__ poffs) {
    if (threadIdx.x == 0) {
        int o = 0; poffs[0] = 0;
        for (int p = 0; p < NPATH; p++) {
            o += ((counts[p] + 127) >> 7) << 7;
            poffs[p + 1] = o;
        }
    }
}

// ---------------- path GEMM 1 (gather): hid[compact] = bf16(silu(x[tok] @ Wp + bp)) ----
__global__ __launch_bounds__(256) void k_path1(const u16* __restrict__ A,
                                               const u16* __restrict__ WT,
                                               const float* __restrict__ pb,
                                               u16* __restrict__ hid,
                                               const int* __restrict__ counts,
                                               const int* __restrict__ tokens,
                                               const int* __restrict__ poffs) {
    int p = blockIdx.z;
    int count = counts[p];
    int m0 = blockIdx.y * 128;
    if (m0 >= count) return;
    int n0 = blockIdx.x * 128;
    int base = poffs[p];
    const u16* BT = WT + (size_t)p * HDIM * HDIM;
    const float* bias = pb + (size_t)p * HDIM;

    __shared__ __align__(16) u16 smem[16384];  // 32KB
    __shared__ int idx[128];
    u16* lA = smem;
    u16* lB = smem + 4096;
    int t = threadIdx.x;
    if (t < 128) {
        int j = m0 + t; if (j > count - 1) j = count - 1;
        idx[t] = tokens[p * B_TOK + j];
    }
    __syncthreads();
    int rowA0 = idx[t >> 2], rowA1 = idx[64 + (t >> 2)];
    int wave = t >> 6, lane = t & 63;
    int quad = lane >> 4, l16 = lane & 15;
    int wr = (wave >> 1) * 64, wc = (wave & 1) * 64;
    f32x4 acc[4][4] = {};
    union UV { uint4 u; bf16x8 v; };
    int c8 = (t & 3) * 8;
    int rb = t >> 2;

    for (int kt = 0; kt < HDIM / 32; kt++) {
        __syncthreads();
        *(uint4*)(lA + t * 8)         = *(const uint4*)(A + (size_t)rowA0 * HDIM + kt * 32 + c8);
        *(uint4*)(lA + (t + 256) * 8) = *(const uint4*)(A + (size_t)rowA1 * HDIM + kt * 32 + c8);
        *(uint4*)(lB + t * 8)         = *(const uint4*)(BT + (size_t)(n0 + rb) * HDIM + kt * 32 + c8);
        *(uint4*)(lB + (t + 256) * 8) = *(const uint4*)(BT + (size_t)(n0 + 64 + rb) * HDIM + kt * 32 + c8);
        __syncthreads();
        bf16x8 av[4], bv[4];
        #pragma unroll
        for (int i = 0; i < 4; i++) {
            UV ua; ua.u = *(uint4*)(lA + ((wr + i * 16 + l16) * 32 + quad * 8));
            av[i] = ua.v;
            UV ub; ub.u = *(uint4*)(lB + ((wc + i * 16 + l16) * 32 + quad * 8));
            bv[i] = ub.v;
        }
        #pragma unroll
        for (int i = 0; i < 4; i++)
            #pragma unroll
            for (int j = 0; j < 4; j++)
                acc[i][j] = mfma_bf16(av[i], bv[j], acc[i][j]);
    }
    __syncthreads();
    #pragma unroll
    for (int j = 0; j < 4; j++) {
        float bj = bias[n0 + wc + j * 16 + l16];
        #pragma unroll
        for (int i = 0; i < 4; i++)
            #pragma unroll
            for (int r = 0; r < 4; r++) {
                int rrow = wr + i * 16 + quad * 4 + r;
                smem[rrow * 128 + wc + j * 16 + l16] = f2bf(silu_f(acc[i][j][r] + bj));
            }
    }
    __syncthreads();
    #pragma unroll
    for (int it = 0; it < 8; it++) {
        int c = t + it * 256;
        int row = c >> 4, cc = (c & 15) * 8;
        *(uint4*)(hid + (size_t)(base + m0 + row) * HDIM + n0 + cc) = *(uint4*)(smem + c * 8);
    }
}

// ---------------- path GEMM 2 (compact): pcomp = bf16(wnorm * (hid @ projWp)) ----------
__global__ __launch_bounds__(256) void k_path2(const u16* __restrict__ hid,
                                               const u16* __restrict__ WT,
                                               const float* __restrict__ wnorm,
                                               u16* __restrict__ pcomp,
                                               const int* __restrict__ counts,
                                               const int* __restrict__ tokens,
                                               const int* __restrict__ poffs) {
    int p = blockIdx.z;
    int count = counts[p];
    int m0 = blockIdx.y * 128;
    if (m0 >= count) return;
    int n0 = blockIdx.x * 128;
    int base = poffs[p];
    const u16* A = hid + (size_t)base * HDIM;
    const u16* BT = WT + (size_t)p * HDIM * HDIM;

    __shared__ __align__(16) u16 smem[16384];  // 32KB
    __shared__ float wv[128];
    u16* lA = smem;
    u16* lB = smem + 4096;
    int t = threadIdx.x;
    if (t < 128) {
        int j = m0 + t; if (j > count - 1) j = count - 1;
        int tok = tokens[p * B_TOK + j];
        wv[t] = wnorm[(size_t)tok * NPATH + p];
    }
    int wave = t >> 6, lane = t & 63;
    int quad = lane >> 4, l16 = lane & 15;
    int wr = (wave >> 1) * 64, wc = (wave & 1) * 64;
    f32x4 acc[4][4] = {};
    union UV { uint4 u; bf16x8 v; };
    int c8 = (t & 3) * 8;
    int rb = t >> 2;

    for (int kt = 0; kt < HDIM / 32; kt++) {
        __syncthreads();
        *(uint4*)(lA + t * 8)         = *(const uint4*)(A + (size_t)(m0 + rb) * HDIM + kt * 32 + c8);
        *(uint4*)(lA + (t + 256) * 8) = *(const uint4*)(A + (size_t)(m0 + 64 + rb) * HDIM + kt * 32 + c8);
        *(uint4*)(lB + t * 8)         = *(const uint4*)(BT + (size_t)(n0 + rb) * HDIM + kt * 32 + c8);
        *(uint4*)(lB + (t + 256) * 8) = *(const uint4*)(BT + (size_t)(n0 + 64 + rb) * HDIM + kt * 32 + c8);
        __syncthreads();
        bf16x8 av[4], bv[4];
        #pragma unroll
        for (int i = 0; i < 4; i++) {
            UV ua; ua.u = *(uint4*)(lA + ((wr + i * 16 + l16) * 32 + quad * 8));
            av[i] = ua.v;
            UV ub; ub.u = *(uint4*)(lB + ((wc + i * 16 + l16) * 32 + quad * 8));
            bv[i] = ub.v;
        }
        #pragma unroll
        for (int i = 0; i < 4; i++)
            #pragma unroll
            for (int j = 0; j < 4; j++)
                acc[i][j] = mfma_bf16(av[i], bv[j], acc[i][j]);
    }
    __syncthreads();
    #pragma unroll
    for (int j = 0; j < 4; j++) {
        #pragma unroll
        for (int i = 0; i < 4; i++)
            #pragma unroll
            for (int r = 0; r < 4; r++) {
                int rrow = wr + i * 16 + quad * 4 + r;
                smem[rrow * 128 + wc + j * 16 + l16] = f2bf(wv[rrow] * acc[i][j][r]);
            }
    }
    __syncthreads();
    #pragma unroll
    for (int it = 0; it < 8; it++) {
        int c = t + it * 256;
        int row = c >> 4, cc = (c & 15) * 8;
        *(uint4*)(pcomp + (size_t)(base + m0 + row) * HDIM + n0 + cc) = *(uint4*)(smem + c * 8);
    }
}

// ---------------- final gather + blend ----------------
__global__ __launch_bounds__(256) void k_blend2(const float* __restrict__ x,
                                                const u16* __restrict__ pcomp,
                                                const uint32_t* __restrict__ slots,
                                                const int* __restrict__ poffs,
                                                const float* __restrict__ blendp,
                                                float* __restrict__ out) {
    int t = threadIdx.x, wave = t >> 6, lane = t & 63;
    int token = blockIdx.x * 4 + wave;
    float alpha = 1.0f / (1.0f + expf(-blendp[0]));
    float beta = 1.0f - alpha;
    uint32_t s0 = slots[(size_t)token * 2];
    uint32_t s1 = slots[(size_t)token * 2 + 1];
    bool f0 = (s0 != 0xFFFFFFFFu), f1 = (s1 != 0xFFFFFFFFu);
    size_t r0 = 0, r1 = 0;
    if (f0) { int p = s0 >> 16, j = s0 & 0xFFFF; r0 = (size_t)(poffs[p] + j) * HDIM; }
    if (f1) { int p = s1 >> 16, j = s1 & 0xFFFF; r1 = (size_t)(poffs[p] + j) * HDIM; }
    const float* xrow = x + (size_t)token * HDIM;
    float* orow = out + (size_t)token * HDIM;
    #pragma unroll
    for (int c = 0; c < 4; c++) {
        int col = c * 256 + lane * 4;
        float4 xv = *(const float4*)(xrow + col);
        float4 o;
        if (f0) {
            uint2 u0 = *(const uint2*)(pcomp + r0 + col);
            float a0 = bf2f(u0.x & 0xFFFF), a1 = bf2f(u0.x >> 16);
            float a2 = bf2f(u0.y & 0xFFFF), a3 = bf2f(u0.y >> 16);
            if (f1) {
                uint2 u1 = *(const uint2*)(pcomp + r1 + col);
                a0 += bf2f(u1.x & 0xFFFF); a1 += bf2f(u1.x >> 16);
                a2 += bf2f(u1.y & 0xFFFF); a3 += bf2f(u1.y >> 16);
            }
            o.x = alpha * a0 + beta * xv.x;
            o.y = alpha * a1 + beta * xv.y;
            o.z = alpha * a2 + beta * xv.z;
            o.w = alpha * a3 + beta * xv.w;
        } else {
            o = xv;
        }
        *(float4*)(orow + col) = o;
    }
}

extern "C" void kernel_launch(void* const* d_in, const int* in_sizes, int n_in,
                              void* d_out, int out_size, void* d_ws, size_t ws_size,
                              hipStream_t stream) {
    const float* x   = (const float*)d_in[0];
    const float* gw1 = (const float*)d_in[1];
    const float* gb1 = (const float*)d_in[2];
    const float* gw2 = (const float*)d_in[3];
    const float* gb2 = (const float*)d_in[4];
    const float* pw  = (const float*)d_in[5];
    const float* pb  = (const float*)d_in[6];
    const float* prw = (const float*)d_in[7];
    const float* blend = (const float*)d_in[8];
    float* out = (float*)d_out;
    float* gate_out = out + (size_t)B_TOK * HDIM;

    char* w = (char*)d_ws;
    size_t o = 0;
    u16* xb      = (u16*)(w + o);   o += (size_t)B_TOK * HDIM * 2;
    u16* pathWT  = (u16*)(w + o);   o += (size_t)NPATH * HDIM * HDIM * 2;
    u16* projWT  = (u16*)(w + o);   o += (size_t)NPATH * HDIM * HDIM * 2;
    // hbuf (fp32, used until topk) overlaid with pcomp (bf16, written after topk)
    size_t uni = o;
    float* hbuf  = (float*)(w + uni);
    u16* pcomp   = (u16*)(w + uni);
    size_t hbuf_sz  = (size_t)B_TOK * HGATE * 4;
    size_t pcomp_sz = (size_t)MAXROWS * HDIM * 2;
    o += (hbuf_sz > pcomp_sz ? hbuf_sz : pcomp_sz);
    u16* hid     = (u16*)(w + o);   o += (size_t)MAXROWS * HDIM * 2;
    float* wnorm = (float*)(w + o); o += (size_t)B_TOK * NPATH * 4;
    int* tokens  = (int*)(w + o);   o += (size_t)NPATH * B_TOK * 4;
    uint32_t* slots = (uint32_t*)(w + o); o += (size_t)B_TOK * 2 * 4;
    int* counts  = (int*)(w + o);   o += 64;
    int* poffs   = (int*)(w + o);   o += 64;

    hipMemsetAsync(counts, 0, NPATH * sizeof(int), stream);
    k_convert_x<<<dim3((B_TOK * HDIM) / 1024), dim3(256), 0, stream>>>(x, xb);
    k_transpose_bf16<<<dim3(32, 32, 8), dim3(32, 8), 0, stream>>>(pw, pathWT);
    k_transpose_bf16<<<dim3(32, 32, 8), dim3(32, 8), 0, stream>>>(prw, projWT);
    k_gemm_gate<<<dim3(HGATE / 64, B_TOK / 64), dim3(256), 0, stream>>>(x, gw1, gb1, hbuf);
    k_gate_topk<<<dim3(B_TOK / 64), dim3(256), 0, stream>>>(hbuf, gw2, gb2, gate_out,
                                                            wnorm, counts, tokens, slots);
    k_prefix<<<dim3(1), dim3(64), 0, stream>>>(counts, poffs);
    k_path1<<<dim3(8, 128, 8), dim3(256), 0, stream>>>(xb, pathWT, pb, hid,
                                                       counts, tokens, poffs);
    k_path2<<<dim3(8, 128, 8), dim3(256), 0, stream>>>(hid, projWT, wnorm, pcomp,
                                                       counts, tokens, poffs);
    k_blend2<<<dim3(B_TOK / 4), dim3(256), 0, stream>>>(x, pcomp, slots, poffs, blend, out);
}

// Round 4
// 688.457 us; speedup vs baseline: 2.4321x; 1.1551x over previous
//
#include <hip/hip_runtime.h>
#include <hip/hip_bf16.h>
#include <cstdint>

#define B_TOK 16384
#define HDIM  1024
#define HGATE 512
#define NPATH 8
#define THRV  0.1f
#define RESSCALE 512.0f
#define MAXROWS (2 * B_TOK + NPATH * 128)   // padded compact rows bound

typedef __bf16 bf16x8 __attribute__((ext_vector_type(8)));
typedef _Float16 f16x8 __attribute__((ext_vector_type(8)));
typedef float  f32x4  __attribute__((ext_vector_type(4)));
typedef unsigned short u16;

__device__ __forceinline__ u16 f2bf(float f) {
    uint32_t u = __float_as_uint(f);
    u += 0x7fff + ((u >> 16) & 1);   // RNE
    return (u16)(u >> 16);
}
__device__ __forceinline__ float bf2f(u16 v) {
    return __uint_as_float((uint32_t)v << 16);
}
union H16 { _Float16 h; u16 u; };
__device__ __forceinline__ u16 f2h(float f) { H16 t; t.h = (_Float16)f; return t.u; }
__device__ __forceinline__ float h2f(u16 b) { H16 t; t.u = b; return (float)t.h; }
__device__ __forceinline__ float silu_f(float a) {
    return a / (1.0f + expf(-a));
}
__device__ __forceinline__ f32x4 mfma_bf16(bf16x8 a, bf16x8 b, f32x4 c) {
    return __builtin_amdgcn_mfma_f32_16x16x32_bf16(a, b, c, 0, 0, 0);
}
__device__ __forceinline__ f32x4 mfma_f16(f16x8 a, f16x8 b, f32x4 c) {
    return __builtin_amdgcn_mfma_f32_16x16x32_f16(a, b, c, 0, 0, 0);
}

// ---------------- x -> bf16 (for paths) + f16 hi + f16 residual*512 (for gate) --------
__global__ void k_convert_x(const float* __restrict__ x, u16* __restrict__ xb,
                            u16* __restrict__ xh, u16* __restrict__ xl) {
    int i = (blockIdx.x * 256 + threadIdx.x) * 4;
    float4 v = *(const float4*)(x + i);
    float vv[4] = {v.x, v.y, v.z, v.w};
    u16 hb[4], hh[4], hl[4];
    #pragma unroll
    for (int c = 0; c < 4; c++) {
        hb[c] = f2bf(vv[c]);
        u16 hi = f2h(vv[c]);
        hh[c] = hi;
        hl[c] = f2h((vv[c] - h2f(hi)) * RESSCALE);
    }
    uint2 ob, oh, ol;
    ob.x = (uint32_t)hb[0] | ((uint32_t)hb[1] << 16);
    ob.y = (uint32_t)hb[2] | ((uint32_t)hb[3] << 16);
    oh.x = (uint32_t)hh[0] | ((uint32_t)hh[1] << 16);
    oh.y = (uint32_t)hh[2] | ((uint32_t)hh[3] << 16);
    ol.x = (uint32_t)hl[0] | ((uint32_t)hl[1] << 16);
    ol.y = (uint32_t)hl[2] | ((uint32_t)hl[3] << 16);
    *(uint2*)(xb + i) = ob;
    *(uint2*)(xh + i) = oh;
    *(uint2*)(xl + i) = ol;
}

// ---------------- W (P,H,H) fp32 -> WT (P,H,H) bf16, WT[p][d][h]=W[p][h][d] ----------------
__global__ void k_transpose_bf16(const float* __restrict__ W, u16* __restrict__ WT) {
    __shared__ float tile[32][33];
    int p = blockIdx.z;
    const float* Wp = W + (size_t)p * HDIM * HDIM;
    u16* WTp = WT + (size_t)p * HDIM * HDIM;
    int d0 = blockIdx.x * 32, h0 = blockIdx.y * 32;
    int tx = threadIdx.x, ty = threadIdx.y;  // (32,8)
    #pragma unroll
    for (int rr = 0; rr < 4; rr++) {
        int r = ty + rr * 8;
        tile[r][tx] = Wp[(size_t)(h0 + r) * HDIM + d0 + tx];
    }
    __syncthreads();
    #pragma unroll
    for (int rr = 0; rr < 4; rr++) {
        int r = ty + rr * 8;
        WTp[(size_t)(d0 + r) * HDIM + h0 + tx] = f2bf(tile[tx][r]);
    }
}

// ---------------- W1 (H,HGATE) fp32 -> W1hT/W1lT (HGATE,H) f16 hi / residual*512 --------
__global__ void k_split_w1(const float* __restrict__ W1, u16* __restrict__ WhT,
                           u16* __restrict__ WlT) {
    __shared__ float tile[32][33];
    int n0 = blockIdx.x * 32, k0 = blockIdx.y * 32;
    int tx = threadIdx.x, ty = threadIdx.y;  // (32,8)
    #pragma unroll
    for (int rr = 0; rr < 4; rr++) {
        int r = ty + rr * 8;
        tile[r][tx] = W1[(size_t)(k0 + r) * HGATE + n0 + tx];
    }
    __syncthreads();
    #pragma unroll
    for (int rr = 0; rr < 4; rr++) {
        int r = ty + rr * 8;
        float v = tile[tx][r];
        u16 hi = f2h(v);
        WhT[(size_t)(n0 + r) * HDIM + k0 + tx] = hi;
        WlT[(size_t)(n0 + r) * HDIM + k0 + tx] = f2h((v - h2f(hi)) * RESSCALE);
    }
}

// ---------------- gate GEMM via 3x f16 MFMA: h = silu(x @ W1 + b1) -------------------
// fp32-equivalent: xh*wh in acc; cross terms (residuals pre-scaled x512) in accm;
// logit = acc + accm/512. f16 2-term split rep error ~2^-24 -> no top-2 flips.
__global__ __launch_bounds__(256) void k_gate_mfma(const u16* __restrict__ Ah,
                                                   const u16* __restrict__ Al,
                                                   const u16* __restrict__ BhT,
                                                   const u16* __restrict__ BlT,
                                                   const float* __restrict__ b1,
                                                   float* __restrict__ Hout) {
    __shared__ __align__(16) u16 smem[16384];  // 32KB: 4 tiles of 128x32 f16
    u16* lAh = smem;
    u16* lAl = smem + 4096;
    u16* lBh = smem + 8192;
    u16* lBl = smem + 12288;
    int t = threadIdx.x;
    int n0 = blockIdx.x * 128, m0 = blockIdx.y * 128;
    int wave = t >> 6, lane = t & 63;
    int quad = lane >> 4, l16 = lane & 15;
    int wr = (wave >> 1) * 64, wc = (wave & 1) * 64;
    f32x4 acc[4][4] = {};
    f32x4 accm[4][4] = {};
    union UV { uint4 u; f16x8 v; };
    int c8 = (t & 3) * 8;
    int rb = t >> 2;

    for (int kt = 0; kt < HDIM / 32; kt++) {
        __syncthreads();
        size_t ga0 = (size_t)(m0 + rb) * HDIM + kt * 32 + c8;
        size_t ga1 = (size_t)(m0 + 64 + rb) * HDIM + kt * 32 + c8;
        size_t gb0 = (size_t)(n0 + rb) * HDIM + kt * 32 + c8;
        size_t gb1 = (size_t)(n0 + 64 + rb) * HDIM + kt * 32 + c8;
        *(uint4*)(lAh + t * 8)         = *(const uint4*)(Ah + ga0);
        *(uint4*)(lAh + (t + 256) * 8) = *(const uint4*)(Ah + ga1);
        *(uint4*)(lAl + t * 8)         = *(const uint4*)(Al + ga0);
        *(uint4*)(lAl + (t + 256) * 8) = *(const uint4*)(Al + ga1);
        *(uint4*)(lBh + t * 8)         = *(const uint4*)(BhT + gb0);
        *(uint4*)(lBh + (t + 256) * 8) = *(const uint4*)(BhT + gb1);
        *(uint4*)(lBl + t * 8)         = *(const uint4*)(BlT + gb0);
        *(uint4*)(lBl + (t + 256) * 8) = *(const uint4*)(BlT + gb1);
        __syncthreads();
        f16x8 avh[4], avl[4], bvh[4], bvl[4];
        #pragma unroll
        for (int i = 0; i < 4; i++) {
            UV u0; u0.u = *(uint4*)(lAh + ((wr + i * 16 + l16) * 32 + quad * 8));
            avh[i] = u0.v;
            UV u1; u1.u = *(uint4*)(lAl + ((wr + i * 16 + l16) * 32 + quad * 8));
            avl[i] = u1.v;
            UV u2; u2.u = *(uint4*)(lBh + ((wc + i * 16 + l16) * 32 + quad * 8));
            bvh[i] = u2.v;
            UV u3; u3.u = *(uint4*)(lBl + ((wc + i * 16 + l16) * 32 + quad * 8));
            bvl[i] = u3.v;
        }
        #pragma unroll
        for (int i = 0; i < 4; i++)
            #pragma unroll
            for (int j = 0; j < 4; j++) {
                acc[i][j]  = mfma_f16(avh[i], bvh[j], acc[i][j]);
                accm[i][j] = mfma_f16(avh[i], bvl[j], accm[i][j]);
                accm[i][j] = mfma_f16(avl[i], bvh[j], accm[i][j]);
            }
    }
    __syncthreads();
    // epilogue: silu(acc + accm/512 + bias) -> Hout fp32, via LDS bounce in 64-row halves
    const float inv_s = 1.0f / RESSCALE;
    float* smf = (float*)smem;  // 64x128 fp32 = 32KB
    #pragma unroll
    for (int half = 0; half < 2; half++) {
        if ((wave >> 1) == half) {
            #pragma unroll
            for (int j = 0; j < 4; j++) {
                float bj = b1[n0 + wc + j * 16 + l16];
                #pragma unroll
                for (int i = 0; i < 4; i++)
                    #pragma unroll
                    for (int r = 0; r < 4; r++) {
                        int rrow = i * 16 + quad * 4 + r;
                        float v = acc[i][j][r] + accm[i][j][r] * inv_s + bj;
                        smf[rrow * 128 + wc + j * 16 + l16] = silu_f(v);
                    }
            }
        }
        __syncthreads();
        #pragma unroll
        for (int it = 0; it < 8; it++) {
            int c = t + it * 256;
            int row = c >> 5, c4 = (c & 31) * 4;
            *(float4*)(Hout + (size_t)(m0 + half * 64 + row) * HGATE + n0 + c4) =
                *(float4*)(smf + c * 4);
        }
        __syncthreads();
    }
}

// ---------------- per-token: logits -> softmax -> top2/threshold + list build --------
__global__ __launch_bounds__(256) void k_gate_topk(const float* __restrict__ Hin,
                                                   const float* __restrict__ W2,
                                                   const float* __restrict__ b2,
                                                   float* __restrict__ gate_out,
                                                   float* __restrict__ wnorm,
                                                   int* __restrict__ counts,
                                                   int* __restrict__ tokens,
                                                   uint32_t* __restrict__ slots) {
    __shared__ float w2t[NPATH * HGATE];
    __shared__ int cnt[NPATH];
    __shared__ int baseS[NPATH];
    __shared__ unsigned short tloc[NPATH][64];
    __shared__ uint32_t sloc[64][2];
    int t = threadIdx.x;
    #pragma unroll
    for (int j = 0; j < 16; j++) {
        int i = t + j * 256;
        w2t[(i & 7) * HGATE + (i >> 3)] = W2[i];
    }
    if (t < NPATH) cnt[t] = 0;
    __syncthreads();
    int wave = t >> 6, lane = t & 63;
    #pragma unroll 1
    for (int it = 0; it < 16; it++) {
        int tl = wave * 16 + it;
        int token = blockIdx.x * 64 + tl;
        const float* hrow = Hin + (size_t)token * HGATE;
        float hv[8];
        {
            float4 h0 = *(const float4*)(hrow + lane * 8);
            float4 h1 = *(const float4*)(hrow + lane * 8 + 4);
            hv[0] = h0.x; hv[1] = h0.y; hv[2] = h0.z; hv[3] = h0.w;
            hv[4] = h1.x; hv[5] = h1.y; hv[6] = h1.z; hv[7] = h1.w;
        }
        float logit[8];
        #pragma unroll
        for (int p = 0; p < 8; p++) {
            float s = 0.0f;
            #pragma unroll
            for (int kk = 0; kk < 8; kk++) s += hv[kk] * w2t[p * HGATE + lane * 8 + kk];
            #pragma unroll
            for (int off = 32; off >= 1; off >>= 1) s += __shfl_xor(s, off);
            logit[p] = s + b2[p];
        }
        float mx = logit[0];
        #pragma unroll
        for (int p = 1; p < 8; p++) mx = fmaxf(mx, logit[p]);
        float pr[8], sum = 0.0f;
        #pragma unroll
        for (int p = 0; p < 8; p++) { pr[p] = expf(logit[p] - mx); sum += pr[p]; }
        float inv = 1.0f / sum;
        #pragma unroll
        for (int p = 0; p < 8; p++) pr[p] *= inv;
        // top-2, ties -> lowest index (matches lax.top_k)
        int i0 = 0; float v0 = pr[0];
        #pragma unroll
        for (int p = 1; p < 8; p++) { if (pr[p] > v0) { v0 = pr[p]; i0 = p; } }
        int i1 = -1; float v1 = -1.0f;
        #pragma unroll
        for (int p = 0; p < 8; p++) { if (p != i0 && pr[p] > v1) { v1 = pr[p]; i1 = p; } }
        float w0 = (v0 > THRV) ? v0 : 0.0f;
        float w1 = (v1 > THRV) ? v1 : 0.0f;
        float total = w0 + w1;
        float invden = (total > 0.0f) ? (1.0f / total) : 1.0f;
        if (lane < 8) {
            float prl = pr[0];
            #pragma unroll
            for (int p = 1; p < 8; p++) prl = (lane == p) ? pr[p] : prl;
            float wl = 0.0f;
            if (lane == i0) wl = w0 * invden;
            if (lane == i1) wl = w1 * invden;
            gate_out[(size_t)token * 8 + lane] = prl;
            wnorm[(size_t)token * 8 + lane] = wl;
        }
        if (lane == 0) {
            uint32_t e0 = 0xFFFFFFFFu, e1 = 0xFFFFFFFFu;
            if (w0 > 0.0f) {
                int j0 = atomicAdd(&cnt[i0], 1);
                tloc[i0][j0] = (unsigned short)tl;
                e0 = ((uint32_t)i0 << 16) | (uint32_t)j0;
            }
            if (w1 > 0.0f) {
                int j1 = atomicAdd(&cnt[i1], 1);
                tloc[i1][j1] = (unsigned short)tl;
                e1 = ((uint32_t)i1 << 16) | (uint32_t)j1;
            }
            sloc[tl][0] = e0; sloc[tl][1] = e1;
        }
    }
    __syncthreads();
    if (t < NPATH) baseS[t] = atomicAdd(&counts[t], cnt[t]);
    __syncthreads();
    for (int p = 0; p < NPATH; p++) {
        int n = cnt[p], b = baseS[p];
        for (int j = t; j < n; j += 256)
            tokens[p * B_TOK + b + j] = blockIdx.x * 64 + tloc[p][j];
    }
    if (t < 64) {
        #pragma unroll
        for (int s = 0; s < 2; s++) {
            uint32_t e = sloc[t][s];
            if (e != 0xFFFFFFFFu) {
                int p = e >> 16;
                int j = (int)(e & 0xFFFFu) + baseS[p];
                e = ((uint32_t)p << 16) | (uint32_t)j;
            }
            slots[(size_t)(blockIdx.x * 64 + t) * 2 + s] = e;
        }
    }
}

// ---------------- padded prefix offsets ----------------
__global__ void k_prefix(const int* __restrict__ counts, int* __restrict__ poffs) {
    if (threadIdx.x == 0) {
        int o = 0; poffs[0] = 0;
        for (int p = 0; p < NPATH; p++) {
            o += ((counts[p] + 127) >> 7) << 7;
            poffs[p + 1] = o;
        }
    }
}

// ---------------- path GEMM 1 (gather): hid[compact] = bf16(silu(x[tok] @ Wp + bp)) ----
__global__ __launch_bounds__(256) void k_path1(const u16* __restrict__ A,
                                               const u16* __restrict__ WT,
                                               const float* __restrict__ pb,
                                               u16* __restrict__ hid,
                                               const int* __restrict__ counts,
                                               const int* __restrict__ tokens,
                                               const int* __restrict__ poffs) {
    int p = blockIdx.z;
    int count = counts[p];
    int m0 = blockIdx.y * 128;
    if (m0 >= count) return;
    int n0 = blockIdx.x * 128;
    int base = poffs[p];
    const u16* BT = WT + (size_t)p * HDIM * HDIM;
    const float* bias = pb + (size_t)p * HDIM;

    __shared__ __align__(16) u16 smem[16384];  // 32KB
    __shared__ int idx[128];
    u16* lA = smem;
    u16* lB = smem + 4096;
    int t = threadIdx.x;
    if (t < 128) {
        int j = m0 + t; if (j > count - 1) j = count - 1;
        idx[t] = tokens[p * B_TOK + j];
    }
    __syncthreads();
    int rowA0 = idx[t >> 2], rowA1 = idx[64 + (t >> 2)];
    int wave = t >> 6, lane = t & 63;
    int quad = lane >> 4, l16 = lane & 15;
    int wr = (wave >> 1) * 64, wc = (wave & 1) * 64;
    f32x4 acc[4][4] = {};
    union UV { uint4 u; bf16x8 v; };
    int c8 = (t & 3) * 8;
    int rb = t >> 2;

    for (int kt = 0; kt < HDIM / 32; kt++) {
        __syncthreads();
        *(uint4*)(lA + t * 8)         = *(const uint4*)(A + (size_t)rowA0 * HDIM + kt * 32 + c8);
        *(uint4*)(lA + (t + 256) * 8) = *(const uint4*)(A + (size_t)rowA1 * HDIM + kt * 32 + c8);
        *(uint4*)(lB + t * 8)         = *(const uint4*)(BT + (size_t)(n0 + rb) * HDIM + kt * 32 + c8);
        *(uint4*)(lB + (t + 256) * 8) = *(const uint4*)(BT + (size_t)(n0 + 64 + rb) * HDIM + kt * 32 + c8);
        __syncthreads();
        bf16x8 av[4], bv[4];
        #pragma unroll
        for (int i = 0; i < 4; i++) {
            UV ua; ua.u = *(uint4*)(lA + ((wr + i * 16 + l16) * 32 + quad * 8));
            av[i] = ua.v;
            UV ub; ub.u = *(uint4*)(lB + ((wc + i * 16 + l16) * 32 + quad * 8));
            bv[i] = ub.v;
        }
        #pragma unroll
        for (int i = 0; i < 4; i++)
            #pragma unroll
            for (int j = 0; j < 4; j++)
                acc[i][j] = mfma_bf16(av[i], bv[j], acc[i][j]);
    }
    __syncthreads();
    #pragma unroll
    for (int j = 0; j < 4; j++) {
        float bj = bias[n0 + wc + j * 16 + l16];
        #pragma unroll
        for (int i = 0; i < 4; i++)
            #pragma unroll
            for (int r = 0; r < 4; r++) {
                int rrow = wr + i * 16 + quad * 4 + r;
                smem[rrow * 128 + wc + j * 16 + l16] = f2bf(silu_f(acc[i][j][r] + bj));
            }
    }
    __syncthreads();
    #pragma unroll
    for (int it = 0; it < 8; it++) {
        int c = t + it * 256;
        int row = c >> 4, cc = (c & 15) * 8;
        *(uint4*)(hid + (size_t)(base + m0 + row) * HDIM + n0 + cc) = *(uint4*)(smem + c * 8);
    }
}

// ---------------- path GEMM 2 (compact): pcomp = bf16(wnorm * (hid @ projWp)) ----------
__global__ __launch_bounds__(256) void k_path2(const u16* __restrict__ hid,
                                               const u16* __restrict__ WT,
                                               const float* __restrict__ wnorm,
                                               u16* __restrict__ pcomp,
                                               const int* __restrict__ counts,
                                               const int* __restrict__ tokens,
                                               const int* __restrict__ poffs) {
    int p = blockIdx.z;
    int count = counts[p];
    int m0 = blockIdx.y * 128;
    if (m0 >= count) return;
    int n0 = blockIdx.x * 128;
    int base = poffs[p];
    const u16* A = hid + (size_t)base * HDIM;
    const u16* BT = WT + (size_t)p * HDIM * HDIM;

    __shared__ __align__(16) u16 smem[16384];  // 32KB
    __shared__ float wv[128];
    u16* lA = smem;
    u16* lB = smem + 4096;
    int t = threadIdx.x;
    if (t < 128) {
        int j = m0 + t; if (j > count - 1) j = count - 1;
        int tok = tokens[p * B_TOK + j];
        wv[t] = wnorm[(size_t)tok * NPATH + p];
    }
    int wave = t >> 6, lane = t & 63;
    int quad = lane >> 4, l16 = lane & 15;
    int wr = (wave >> 1) * 64, wc = (wave & 1) * 64;
    f32x4 acc[4][4] = {};
    union UV { uint4 u; bf16x8 v; };
    int c8 = (t & 3) * 8;
    int rb = t >> 2;

    for (int kt = 0; kt < HDIM / 32; kt++) {
        __syncthreads();
        *(uint4*)(lA + t * 8)         = *(const uint4*)(A + (size_t)(m0 + rb) * HDIM + kt * 32 + c8);
        *(uint4*)(lA + (t + 256) * 8) = *(const uint4*)(A + (size_t)(m0 + 64 + rb) * HDIM + kt * 32 + c8);
        *(uint4*)(lB + t * 8)         = *(const uint4*)(BT + (size_t)(n0 + rb) * HDIM + kt * 32 + c8);
        *(uint4*)(lB + (t + 256) * 8) = *(const uint4*)(BT + (size_t)(n0 + 64 + rb) * HDIM + kt * 32 + c8);
        __syncthreads();
        bf16x8 av[4], bv[4];
        #pragma unroll
        for (int i = 0; i < 4; i++) {
            UV ua; ua.u = *(uint4*)(lA + ((wr + i * 16 + l16) * 32 + quad * 8));
            av[i] = ua.v;
            UV ub; ub.u = *(uint4*)(lB + ((wc + i * 16 + l16) * 32 + quad * 8));
            bv[i] = ub.v;
        }
        #pragma unroll
        for (int i = 0; i < 4; i++)
            #pragma unroll
            for (int j = 0; j < 4; j++)
                acc[i][j] = mfma_bf16(av[i], bv[j], acc[i][j]);
    }
    __syncthreads();
    #pragma unroll
    for (int j = 0; j < 4; j++) {
        #pragma unroll
        for (int i = 0; i < 4; i++)
            #pragma unroll
            for (int r = 0; r < 4; r++) {
                int rrow = wr + i * 16 + quad * 4 + r;
                smem[rrow * 128 + wc + j * 16 + l16] = f2bf(wv[rrow] * acc[i][j][r]);
            }
    }
    __syncthreads();
    #pragma unroll
    for (int it = 0; it < 8; it++) {
        int c = t + it * 256;
        int row = c >> 4, cc = (c & 15) * 8;
        *(uint4*)(pcomp + (size_t)(base + m0 + row) * HDIM + n0 + cc) = *(uint4*)(smem + c * 8);
    }
}

// ---------------- final gather + blend ----------------
__global__ __launch_bounds__(256) void k_blend2(const float* __restrict__ x,
                                                const u16* __restrict__ pcomp,
                                                const uint32_t* __restrict__ slots,
                                                const int* __restrict__ poffs,
                                                const float* __restrict__ blendp,
                                                float* __restrict__ out) {
    int t = threadIdx.x, wave = t >> 6, lane = t & 63;
    int token = blockIdx.x * 4 + wave;
    float alpha = 1.0f / (1.0f + expf(-blendp[0]));
    float beta = 1.0f - alpha;
    uint32_t s0 = slots[(size_t)token * 2];
    uint32_t s1 = slots[(size_t)token * 2 + 1];
    bool f0 = (s0 != 0xFFFFFFFFu), f1 = (s1 != 0xFFFFFFFFu);
    size_t r0 = 0, r1 = 0;
    if (f0) { int p = s0 >> 16, j = s0 & 0xFFFF; r0 = (size_t)(poffs[p] + j) * HDIM; }
    if (f1) { int p = s1 >> 16, j = s1 & 0xFFFF; r1 = (size_t)(poffs[p] + j) * HDIM; }
    const float* xrow = x + (size_t)token * HDIM;
    float* orow = out + (size_t)token * HDIM;
    #pragma unroll
    for (int c = 0; c < 4; c++) {
        int col = c * 256 + lane * 4;
        float4 xv = *(const float4*)(xrow + col);
        float4 o;
        if (f0) {
            uint2 u0 = *(const uint2*)(pcomp + r0 + col);
            float a0 = bf2f(u0.x & 0xFFFF), a1 = bf2f(u0.x >> 16);
            float a2 = bf2f(u0.y & 0xFFFF), a3 = bf2f(u0.y >> 16);
            if (f1) {
                uint2 u1 = *(const uint2*)(pcomp + r1 + col);
                a0 += bf2f(u1.x & 0xFFFF); a1 += bf2f(u1.x >> 16);
                a2 += bf2f(u1.y & 0xFFFF); a3 += bf2f(u1.y >> 16);
            }
            o.x = alpha * a0 + beta * xv.x;
            o.y = alpha * a1 + beta * xv.y;
            o.z = alpha * a2 + beta * xv.z;
            o.w = alpha * a3 + beta * xv.w;
        } else {
            o = xv;
        }
        *(float4*)(orow + col) = o;
    }
}

extern "C" void kernel_launch(void* const* d_in, const int* in_sizes, int n_in,
                              void* d_out, int out_size, void* d_ws, size_t ws_size,
                              hipStream_t stream) {
    const float* x   = (const float*)d_in[0];
    const float* gw1 = (const float*)d_in[1];
    const float* gb1 = (const float*)d_in[2];
    const float* gw2 = (const float*)d_in[3];
    const float* gb2 = (const float*)d_in[4];
    const float* pw  = (const float*)d_in[5];
    const float* pb  = (const float*)d_in[6];
    const float* prw = (const float*)d_in[7];
    const float* blend = (const float*)d_in[8];
    float* out = (float*)d_out;
    float* gate_out = out + (size_t)B_TOK * HDIM;

    char* w = (char*)d_ws;
    size_t o = 0;
    u16* xb      = (u16*)(w + o);   o += (size_t)B_TOK * HDIM * 2;
    u16* pathWT  = (u16*)(w + o);   o += (size_t)NPATH * HDIM * HDIM * 2;
    u16* projWT  = (u16*)(w + o);   o += (size_t)NPATH * HDIM * HDIM * 2;
    u16* w1hT    = (u16*)(w + o);   o += (size_t)HGATE * HDIM * 2;
    u16* w1lT    = (u16*)(w + o);   o += (size_t)HGATE * HDIM * 2;
    // hbuf (fp32, used until topk) overlaid with pcomp (bf16, written after topk)
    size_t uni = o;
    float* hbuf  = (float*)(w + uni);
    u16* pcomp   = (u16*)(w + uni);
    size_t hbuf_sz  = (size_t)B_TOK * HGATE * 4;
    size_t pcomp_sz = (size_t)MAXROWS * HDIM * 2;
    o += (hbuf_sz > pcomp_sz ? hbuf_sz : pcomp_sz);
    // xh/xl (f16 hi+residual of x, dead after gate GEMM) overlaid with hid (written by path1)
    size_t uni2 = o;
    u16* xh16    = (u16*)(w + uni2);                           // B_TOK*HDIM*2
    u16* xl16    = (u16*)(w + uni2 + (size_t)B_TOK * HDIM * 2); // B_TOK*HDIM*2
    u16* hid     = (u16*)(w + uni2);
    o += (size_t)MAXROWS * HDIM * 2;   // 69.2MB >= 2 * 33.6MB
    float* wnorm = (float*)(w + o); o += (size_t)B_TOK * NPATH * 4;
    int* tokens  = (int*)(w + o);   o += (size_t)NPATH * B_TOK * 4;
    uint32_t* slots = (uint32_t*)(w + o); o += (size_t)B_TOK * 2 * 4;
    int* counts  = (int*)(w + o);   o += 64;
    int* poffs   = (int*)(w + o);   o += 64;

    hipMemsetAsync(counts, 0, NPATH * sizeof(int), stream);
    k_convert_x<<<dim3((B_TOK * HDIM) / 1024), dim3(256), 0, stream>>>(x, xb, xh16, xl16);
    k_split_w1<<<dim3(HGATE / 32, HDIM / 32), dim3(32, 8), 0, stream>>>(gw1, w1hT, w1lT);
    k_transpose_bf16<<<dim3(32, 32, 8), dim3(32, 8), 0, stream>>>(pw, pathWT);
    k_transpose_bf16<<<dim3(32, 32, 8), dim3(32, 8), 0, stream>>>(prw, projWT);
    k_gate_mfma<<<dim3(HGATE / 128, B_TOK / 128), dim3(256), 0, stream>>>(
        xh16, xl16, w1hT, w1lT, gb1, hbuf);
    k_gate_topk<<<dim3(B_TOK / 64), dim3(256), 0, stream>>>(hbuf, gw2, gb2, gate_out,
                                                            wnorm, counts, tokens, slots);
    k_prefix<<<dim3(1), dim3(64), 0, stream>>>(counts, poffs);
    k_path1<<<dim3(8, 128, 8), dim3(256), 0, stream>>>(xb, pathWT, pb, hid,
                                                       counts, tokens, poffs);
    k_path2<<<dim3(8, 128, 8), dim3(256), 0, stream>>>(hid, projWT, wnorm, pcomp,
                                                       counts, tokens, poffs);
    k_blend2<<<dim3(B_TOK / 4), dim3(256), 0, stream>>>(x, pcomp, slots, poffs, blend, out);
}

// Round 5
// 604.634 us; speedup vs baseline: 2.7692x; 1.1386x over previous
//
#include <hip/hip_runtime.h>
#include <hip/hip_bf16.h>
#include <cstdint>

#define B_TOK 16384
#define HDIM  1024
#define HGATE 512
#define NPATH 8
#define THRV  0.1f
#define RESSCALE 512.0f
#define MAXROWS (2 * B_TOK + NPATH * 128)   // padded compact rows bound

typedef __bf16 bf16x8 __attribute__((ext_vector_type(8)));
typedef _Float16 f16x8 __attribute__((ext_vector_type(8)));
typedef float  f32x4  __attribute__((ext_vector_type(4)));
typedef unsigned short u16;

__device__ __forceinline__ u16 f2bf(float f) {
    uint32_t u = __float_as_uint(f);
    u += 0x7fff + ((u >> 16) & 1);   // RNE
    return (u16)(u >> 16);
}
__device__ __forceinline__ float bf2f(u16 v) {
    return __uint_as_float((uint32_t)v << 16);
}
union H16 { _Float16 h; u16 u; };
__device__ __forceinline__ u16 f2h(float f) { H16 t; t.h = (_Float16)f; return t.u; }
__device__ __forceinline__ float h2f(u16 b) { H16 t; t.u = b; return (float)t.h; }
__device__ __forceinline__ float silu_f(float a) {
    return a / (1.0f + expf(-a));
}
__device__ __forceinline__ f32x4 mfma_bf16(bf16x8 a, bf16x8 b, f32x4 c) {
    return __builtin_amdgcn_mfma_f32_16x16x32_bf16(a, b, c, 0, 0, 0);
}
__device__ __forceinline__ f32x4 mfma_f16(f16x8 a, f16x8 b, f32x4 c) {
    return __builtin_amdgcn_mfma_f32_16x16x32_f16(a, b, c, 0, 0, 0);
}
// async global->LDS 16B/lane; lds base must be wave-uniform (dest = base + lane*16)
__device__ __forceinline__ void async_lds16(const u16* g, u16* l) {
    __builtin_amdgcn_global_load_lds((const __attribute__((address_space(1))) uint32_t*)g,
                                     (__attribute__((address_space(3))) uint32_t*)l,
                                     16, 0, 0);
}

// ---------------- x -> bf16 (for paths) + f16 hi + f16 residual*512 (for gate) --------
__global__ void k_convert_x(const float* __restrict__ x, u16* __restrict__ xb,
                            u16* __restrict__ xh, u16* __restrict__ xl) {
    int i = (blockIdx.x * 256 + threadIdx.x) * 4;
    float4 v = *(const float4*)(x + i);
    float vv[4] = {v.x, v.y, v.z, v.w};
    u16 hb[4], hh[4], hl[4];
    #pragma unroll
    for (int c = 0; c < 4; c++) {
        hb[c] = f2bf(vv[c]);
        u16 hi = f2h(vv[c]);
        hh[c] = hi;
        hl[c] = f2h((vv[c] - h2f(hi)) * RESSCALE);
    }
    uint2 ob, oh, ol;
    ob.x = (uint32_t)hb[0] | ((uint32_t)hb[1] << 16);
    ob.y = (uint32_t)hb[2] | ((uint32_t)hb[3] << 16);
    oh.x = (uint32_t)hh[0] | ((uint32_t)hh[1] << 16);
    oh.y = (uint32_t)hh[2] | ((uint32_t)hh[3] << 16);
    ol.x = (uint32_t)hl[0] | ((uint32_t)hl[1] << 16);
    ol.y = (uint32_t)hl[2] | ((uint32_t)hl[3] << 16);
    *(uint2*)(xb + i) = ob;
    *(uint2*)(xh + i) = oh;
    *(uint2*)(xl + i) = ol;
}

// ---------------- W (P,H,H) fp32 -> WT (P,H,H) bf16, WT[p][d][h]=W[p][h][d] ----------------
__global__ void k_transpose_bf16(const float* __restrict__ W, u16* __restrict__ WT) {
    __shared__ float tile[32][33];
    int p = blockIdx.z;
    const float* Wp = W + (size_t)p * HDIM * HDIM;
    u16* WTp = WT + (size_t)p * HDIM * HDIM;
    int d0 = blockIdx.x * 32, h0 = blockIdx.y * 32;
    int tx = threadIdx.x, ty = threadIdx.y;  // (32,8)
    #pragma unroll
    for (int rr = 0; rr < 4; rr++) {
        int r = ty + rr * 8;
        tile[r][tx] = Wp[(size_t)(h0 + r) * HDIM + d0 + tx];
    }
    __syncthreads();
    #pragma unroll
    for (int rr = 0; rr < 4; rr++) {
        int r = ty + rr * 8;
        WTp[(size_t)(d0 + r) * HDIM + h0 + tx] = f2bf(tile[tx][r]);
    }
}

// ---------------- W1 (H,HGATE) fp32 -> W1hT/W1lT (HGATE,H) f16 hi / residual*512 --------
__global__ void k_split_w1(const float* __restrict__ W1, u16* __restrict__ WhT,
                           u16* __restrict__ WlT) {
    __shared__ float tile[32][33];
    int n0 = blockIdx.x * 32, k0 = blockIdx.y * 32;
    int tx = threadIdx.x, ty = threadIdx.y;  // (32,8)
    #pragma unroll
    for (int rr = 0; rr < 4; rr++) {
        int r = ty + rr * 8;
        tile[r][tx] = W1[(size_t)(k0 + r) * HGATE + n0 + tx];
    }
    __syncthreads();
    #pragma unroll
    for (int rr = 0; rr < 4; rr++) {
        int r = ty + rr * 8;
        float v = tile[tx][r];
        u16 hi = f2h(v);
        WhT[(size_t)(n0 + r) * HDIM + k0 + tx] = hi;
        WlT[(size_t)(n0 + r) * HDIM + k0 + tx] = f2h((v - h2f(hi)) * RESSCALE);
    }
}

// ---------------- gate GEMM via 3x f16 MFMA: h = silu(x @ W1 + b1) -------------------
__global__ __launch_bounds__(256) void k_gate_mfma(const u16* __restrict__ Ah,
                                                   const u16* __restrict__ Al,
                                                   const u16* __restrict__ BhT,
                                                   const u16* __restrict__ BlT,
                                                   const float* __restrict__ b1,
                                                   float* __restrict__ Hout) {
    __shared__ __align__(16) u16 smem[16384];  // 32KB: 4 tiles of 128x32 f16
    u16* lAh = smem;
    u16* lAl = smem + 4096;
    u16* lBh = smem + 8192;
    u16* lBl = smem + 12288;
    int t = threadIdx.x;
    int n0 = blockIdx.x * 128, m0 = blockIdx.y * 128;
    int wave = t >> 6, lane = t & 63;
    int quad = lane >> 4, l16 = lane & 15;
    int wr = (wave >> 1) * 64, wc = (wave & 1) * 64;
    f32x4 acc[4][4] = {};
    f32x4 accm[4][4] = {};
    union UV { uint4 u; f16x8 v; };
    int c8 = (t & 3) * 8;
    int rb = t >> 2;
    int wb = wave * 512;   // wave-uniform LDS base (u16 elems) for async staging

    for (int kt = 0; kt < HDIM / 32; kt++) {
        __syncthreads();
        size_t ga0 = (size_t)(m0 + rb) * HDIM + kt * 32 + c8;
        size_t ga1 = (size_t)(m0 + 64 + rb) * HDIM + kt * 32 + c8;
        size_t gb0 = (size_t)(n0 + rb) * HDIM + kt * 32 + c8;
        size_t gb1 = (size_t)(n0 + 64 + rb) * HDIM + kt * 32 + c8;
        async_lds16(Ah + ga0, lAh + wb);
        async_lds16(Ah + ga1, lAh + 2048 + wb);
        async_lds16(Al + ga0, lAl + wb);
        async_lds16(Al + ga1, lAl + 2048 + wb);
        async_lds16(BhT + gb0, lBh + wb);
        async_lds16(BhT + gb1, lBh + 2048 + wb);
        async_lds16(BlT + gb0, lBl + wb);
        async_lds16(BlT + gb1, lBl + 2048 + wb);
        __syncthreads();
        f16x8 avh[4], avl[4], bvh[4], bvl[4];
        #pragma unroll
        for (int i = 0; i < 4; i++) {
            UV u0; u0.u = *(uint4*)(lAh + ((wr + i * 16 + l16) * 32 + quad * 8));
            avh[i] = u0.v;
            UV u1; u1.u = *(uint4*)(lAl + ((wr + i * 16 + l16) * 32 + quad * 8));
            avl[i] = u1.v;
            UV u2; u2.u = *(uint4*)(lBh + ((wc + i * 16 + l16) * 32 + quad * 8));
            bvh[i] = u2.v;
            UV u3; u3.u = *(uint4*)(lBl + ((wc + i * 16 + l16) * 32 + quad * 8));
            bvl[i] = u3.v;
        }
        #pragma unroll
        for (int i = 0; i < 4; i++)
            #pragma unroll
            for (int j = 0; j < 4; j++) {
                acc[i][j]  = mfma_f16(avh[i], bvh[j], acc[i][j]);
                accm[i][j] = mfma_f16(avh[i], bvl[j], accm[i][j]);
                accm[i][j] = mfma_f16(avl[i], bvh[j], accm[i][j]);
            }
    }
    __syncthreads();
    // epilogue: silu(acc + accm/512 + bias) -> Hout fp32, via LDS bounce in 64-row halves
    const float inv_s = 1.0f / RESSCALE;
    float* smf = (float*)smem;  // 64x128 fp32 = 32KB
    #pragma unroll
    for (int half = 0; half < 2; half++) {
        if ((wave >> 1) == half) {
            #pragma unroll
            for (int j = 0; j < 4; j++) {
                float bj = b1[n0 + wc + j * 16 + l16];
                #pragma unroll
                for (int i = 0; i < 4; i++)
                    #pragma unroll
                    for (int r = 0; r < 4; r++) {
                        int rrow = i * 16 + quad * 4 + r;
                        float v = acc[i][j][r] + accm[i][j][r] * inv_s + bj;
                        smf[rrow * 128 + wc + j * 16 + l16] = silu_f(v);
                    }
            }
        }
        __syncthreads();
        #pragma unroll
        for (int it = 0; it < 8; it++) {
            int c = t + it * 256;
            int row = c >> 5, c4 = (c & 31) * 4;
            *(float4*)(Hout + (size_t)(m0 + half * 64 + row) * HGATE + n0 + c4) =
                *(float4*)(smf + c * 4);
        }
        __syncthreads();
    }
}

// ---------------- per-token: logits -> softmax -> top2/threshold + list build --------
__global__ __launch_bounds__(256) void k_gate_topk(const float* __restrict__ Hin,
                                                   const float* __restrict__ W2,
                                                   const float* __restrict__ b2,
                                                   float* __restrict__ gate_out,
                                                   float* __restrict__ wnorm,
                                                   int* __restrict__ counts,
                                                   int* __restrict__ tokens,
                                                   uint32_t* __restrict__ slots) {
    __shared__ float w2t[NPATH * HGATE];
    __shared__ int cnt[NPATH];
    __shared__ int baseS[NPATH];
    __shared__ unsigned short tloc[NPATH][64];
    __shared__ uint32_t sloc[64][2];
    int t = threadIdx.x;
    #pragma unroll
    for (int j = 0; j < 16; j++) {
        int i = t + j * 256;
        w2t[(i & 7) * HGATE + (i >> 3)] = W2[i];
    }
    if (t < NPATH) cnt[t] = 0;
    __syncthreads();
    int wave = t >> 6, lane = t & 63;
    #pragma unroll 1
    for (int it = 0; it < 16; it++) {
        int tl = wave * 16 + it;
        int token = blockIdx.x * 64 + tl;
        const float* hrow = Hin + (size_t)token * HGATE;
        float hv[8];
        {
            float4 h0 = *(const float4*)(hrow + lane * 8);
            float4 h1 = *(const float4*)(hrow + lane * 8 + 4);
            hv[0] = h0.x; hv[1] = h0.y; hv[2] = h0.z; hv[3] = h0.w;
            hv[4] = h1.x; hv[5] = h1.y; hv[6] = h1.z; hv[7] = h1.w;
        }
        float logit[8];
        #pragma unroll
        for (int p = 0; p < 8; p++) {
            float s = 0.0f;
            #pragma unroll
            for (int kk = 0; kk < 8; kk++) s += hv[kk] * w2t[p * HGATE + lane * 8 + kk];
            #pragma unroll
            for (int off = 32; off >= 1; off >>= 1) s += __shfl_xor(s, off);
            logit[p] = s + b2[p];
        }
        float mx = logit[0];
        #pragma unroll
        for (int p = 1; p < 8; p++) mx = fmaxf(mx, logit[p]);
        float pr[8], sum = 0.0f;
        #pragma unroll
        for (int p = 0; p < 8; p++) { pr[p] = expf(logit[p] - mx); sum += pr[p]; }
        float inv = 1.0f / sum;
        #pragma unroll
        for (int p = 0; p < 8; p++) pr[p] *= inv;
        // top-2, ties -> lowest index (matches lax.top_k)
        int i0 = 0; float v0 = pr[0];
        #pragma unroll
        for (int p = 1; p < 8; p++) { if (pr[p] > v0) { v0 = pr[p]; i0 = p; } }
        int i1 = -1; float v1 = -1.0f;
        #pragma unroll
        for (int p = 0; p < 8; p++) { if (p != i0 && pr[p] > v1) { v1 = pr[p]; i1 = p; } }
        float w0 = (v0 > THRV) ? v0 : 0.0f;
        float w1 = (v1 > THRV) ? v1 : 0.0f;
        float total = w0 + w1;
        float invden = (total > 0.0f) ? (1.0f / total) : 1.0f;
        if (lane < 8) {
            float prl = pr[0];
            #pragma unroll
            for (int p = 1; p < 8; p++) prl = (lane == p) ? pr[p] : prl;
            float wl = 0.0f;
            if (lane == i0) wl = w0 * invden;
            if (lane == i1) wl = w1 * invden;
            gate_out[(size_t)token * 8 + lane] = prl;
            wnorm[(size_t)token * 8 + lane] = wl;
        }
        if (lane == 0) {
            uint32_t e0 = 0xFFFFFFFFu, e1 = 0xFFFFFFFFu;
            if (w0 > 0.0f) {
                int j0 = atomicAdd(&cnt[i0], 1);
                tloc[i0][j0] = (unsigned short)tl;
                e0 = ((uint32_t)i0 << 16) | (uint32_t)j0;
            }
            if (w1 > 0.0f) {
                int j1 = atomicAdd(&cnt[i1], 1);
                tloc[i1][j1] = (unsigned short)tl;
                e1 = ((uint32_t)i1 << 16) | (uint32_t)j1;
            }
            sloc[tl][0] = e0; sloc[tl][1] = e1;
        }
    }
    __syncthreads();
    if (t < NPATH) baseS[t] = atomicAdd(&counts[t], cnt[t]);
    __syncthreads();
    for (int p = 0; p < NPATH; p++) {
        int n = cnt[p], b = baseS[p];
        for (int j = t; j < n; j += 256)
            tokens[p * B_TOK + b + j] = blockIdx.x * 64 + tloc[p][j];
    }
    if (t < 64) {
        #pragma unroll
        for (int s = 0; s < 2; s++) {
            uint32_t e = sloc[t][s];
            if (e != 0xFFFFFFFFu) {
                int p = e >> 16;
                int j = (int)(e & 0xFFFFu) + baseS[p];
                e = ((uint32_t)p << 16) | (uint32_t)j;
            }
            slots[(size_t)(blockIdx.x * 64 + t) * 2 + s] = e;
        }
    }
}

// ---------------- padded prefix offsets ----------------
__global__ void k_prefix(const int* __restrict__ counts, int* __restrict__ poffs) {
    if (threadIdx.x == 0) {
        int o = 0; poffs[0] = 0;
        for (int p = 0; p < NPATH; p++) {
            o += ((counts[p] + 127) >> 7) << 7;
            poffs[p + 1] = o;
        }
    }
}

// ---------------- path GEMM 1 (gather): hid[compact] = bf16(silu(x[tok] @ Wp + bp)) ----
__global__ __launch_bounds__(256) void k_path1(const u16* __restrict__ A,
                                               const u16* __restrict__ WT,
                                               const float* __restrict__ pb,
                                               u16* __restrict__ hid,
                                               const int* __restrict__ counts,
                                               const int* __restrict__ tokens,
                                               const int* __restrict__ poffs) {
    int p = blockIdx.z;
    int count = counts[p];
    int m0 = blockIdx.y * 128;
    if (m0 >= count) return;
    int n0 = blockIdx.x * 128;
    int base = poffs[p];
    const u16* BT = WT + (size_t)p * HDIM * HDIM;
    const float* bias = pb + (size_t)p * HDIM;

    __shared__ __align__(16) u16 smem[16384];  // 32KB
    __shared__ int idx[128];
    u16* lA = smem;
    u16* lB = smem + 4096;
    int t = threadIdx.x;
    if (t < 128) {
        int j = m0 + t; if (j > count - 1) j = count - 1;
        idx[t] = tokens[p * B_TOK + j];
    }
    __syncthreads();
    int rowA0 = idx[t >> 2], rowA1 = idx[64 + (t >> 2)];
    int wave = t >> 6, lane = t & 63;
    int quad = lane >> 4, l16 = lane & 15;
    int wr = (wave >> 1) * 64, wc = (wave & 1) * 64;
    f32x4 acc[4][4] = {};
    union UV { uint4 u; bf16x8 v; };
    int c8 = (t & 3) * 8;
    int rb = t >> 2;
    int wb = wave * 512;

    for (int kt = 0; kt < HDIM / 32; kt++) {
        __syncthreads();
        async_lds16(A + (size_t)rowA0 * HDIM + kt * 32 + c8, lA + wb);
        async_lds16(A + (size_t)rowA1 * HDIM + kt * 32 + c8, lA + 2048 + wb);
        async_lds16(BT + (size_t)(n0 + rb) * HDIM + kt * 32 + c8, lB + wb);
        async_lds16(BT + (size_t)(n0 + 64 + rb) * HDIM + kt * 32 + c8, lB + 2048 + wb);
        __syncthreads();
        bf16x8 av[4], bv[4];
        #pragma unroll
        for (int i = 0; i < 4; i++) {
            UV ua; ua.u = *(uint4*)(lA + ((wr + i * 16 + l16) * 32 + quad * 8));
            av[i] = ua.v;
            UV ub; ub.u = *(uint4*)(lB + ((wc + i * 16 + l16) * 32 + quad * 8));
            bv[i] = ub.v;
        }
        #pragma unroll
        for (int i = 0; i < 4; i++)
            #pragma unroll
            for (int j = 0; j < 4; j++)
                acc[i][j] = mfma_bf16(av[i], bv[j], acc[i][j]);
    }
    __syncthreads();
    #pragma unroll
    for (int j = 0; j < 4; j++) {
        float bj = bias[n0 + wc + j * 16 + l16];
        #pragma unroll
        for (int i = 0; i < 4; i++)
            #pragma unroll
            for (int r = 0; r < 4; r++) {
                int rrow = wr + i * 16 + quad * 4 + r;
                smem[rrow * 128 + wc + j * 16 + l16] = f2bf(silu_f(acc[i][j][r] + bj));
            }
    }
    __syncthreads();
    #pragma unroll
    for (int it = 0; it < 8; it++) {
        int c = t + it * 256;
        int row = c >> 4, cc = (c & 15) * 8;
        *(uint4*)(hid + (size_t)(base + m0 + row) * HDIM + n0 + cc) = *(uint4*)(smem + c * 8);
    }
}

// ---------------- path GEMM 2 (compact): pcomp = bf16(wnorm * (hid @ projWp)) ----------
__global__ __launch_bounds__(256) void k_path2(const u16* __restrict__ hid,
                                               const u16* __restrict__ WT,
                                               const float* __restrict__ wnorm,
                                               u16* __restrict__ pcomp,
                                               const int* __restrict__ counts,
                                               const int* __restrict__ tokens,
                                               const int* __restrict__ poffs) {
    int p = blockIdx.z;
    int count = counts[p];
    int m0 = blockIdx.y * 128;
    if (m0 >= count) return;
    int n0 = blockIdx.x * 128;
    int base = poffs[p];
    const u16* A = hid + (size_t)base * HDIM;
    const u16* BT = WT + (size_t)p * HDIM * HDIM;

    __shared__ __align__(16) u16 smem[16384];  // 32KB
    __shared__ float wv[128];
    u16* lA = smem;
    u16* lB = smem + 4096;
    int t = threadIdx.x;
    if (t < 128) {
        int j = m0 + t; if (j > count - 1) j = count - 1;
        int tok = tokens[p * B_TOK + j];
        wv[t] = wnorm[(size_t)tok * NPATH + p];
    }
    int wave = t >> 6, lane = t & 63;
    int quad = lane >> 4, l16 = lane & 15;
    int wr = (wave >> 1) * 64, wc = (wave & 1) * 64;
    f32x4 acc[4][4] = {};
    union UV { uint4 u; bf16x8 v; };
    int c8 = (t & 3) * 8;
    int rb = t >> 2;
    int wb = wave * 512;

    for (int kt = 0; kt < HDIM / 32; kt++) {
        __syncthreads();
        async_lds16(A + (size_t)(m0 + rb) * HDIM + kt * 32 + c8, lA + wb);
        async_lds16(A + (size_t)(m0 + 64 + rb) * HDIM + kt * 32 + c8, lA + 2048 + wb);
        async_lds16(BT + (size_t)(n0 + rb) * HDIM + kt * 32 + c8, lB + wb);
        async_lds16(BT + (size_t)(n0 + 64 + rb) * HDIM + kt * 32 + c8, lB + 2048 + wb);
        __syncthreads();
        bf16x8 av[4], bv[4];
        #pragma unroll
        for (int i = 0; i < 4; i++) {
            UV ua; ua.u = *(uint4*)(lA + ((wr + i * 16 + l16) * 32 + quad * 8));
            av[i] = ua.v;
            UV ub; ub.u = *(uint4*)(lB + ((wc + i * 16 + l16) * 32 + quad * 8));
            bv[i] = ub.v;
        }
        #pragma unroll
        for (int i = 0; i < 4; i++)
            #pragma unroll
            for (int j = 0; j < 4; j++)
                acc[i][j] = mfma_bf16(av[i], bv[j], acc[i][j]);
    }
    __syncthreads();
    #pragma unroll
    for (int j = 0; j < 4; j++) {
        #pragma unroll
        for (int i = 0; i < 4; i++)
            #pragma unroll
            for (int r = 0; r < 4; r++) {
                int rrow = wr + i * 16 + quad * 4 + r;
                smem[rrow * 128 + wc + j * 16 + l16] = f2bf(wv[rrow] * acc[i][j][r]);
            }
    }
    __syncthreads();
    #pragma unroll
    for (int it = 0; it < 8; it++) {
        int c = t + it * 256;
        int row = c >> 4, cc = (c & 15) * 8;
        *(uint4*)(pcomp + (size_t)(base + m0 + row) * HDIM + n0 + cc) = *(uint4*)(smem + c * 8);
    }
}

// ---------------- final gather + blend ----------------
__global__ __launch_bounds__(256) void k_blend2(const float* __restrict__ x,
                                                const u16* __restrict__ pcomp,
                                                const uint32_t* __restrict__ slots,
                                                const int* __restrict__ poffs,
                                                const float* __restrict__ blendp,
                                                float* __restrict__ out) {
    int t = threadIdx.x, wave = t >> 6, lane = t & 63;
    int token = blockIdx.x * 4 + wave;
    float alpha = 1.0f / (1.0f + expf(-blendp[0]));
    float beta = 1.0f - alpha;
    uint32_t s0 = slots[(size_t)token * 2];
    uint32_t s1 = slots[(size_t)token * 2 + 1];
    bool f0 = (s0 != 0xFFFFFFFFu), f1 = (s1 != 0xFFFFFFFFu);
    size_t r0 = 0, r1 = 0;
    if (f0) { int p = s0 >> 16, j = s0 & 0xFFFF; r0 = (size_t)(poffs[p] + j) * HDIM; }
    if (f1) { int p = s1 >> 16, j = s1 & 0xFFFF; r1 = (size_t)(poffs[p] + j) * HDIM; }
    const float* xrow = x + (size_t)token * HDIM;
    float* orow = out + (size_t)token * HDIM;
    #pragma unroll
    for (int c = 0; c < 4; c++) {
        int col = c * 256 + lane * 4;
        float4 xv = *(const float4*)(xrow + col);
        float4 o;
        if (f0) {
            uint2 u0 = *(const uint2*)(pcomp + r0 + col);
            float a0 = bf2f(u0.x & 0xFFFF), a1 = bf2f(u0.x >> 16);
            float a2 = bf2f(u0.y & 0xFFFF), a3 = bf2f(u0.y >> 16);
            if (f1) {
                uint2 u1 = *(const uint2*)(pcomp + r1 + col);
                a0 += bf2f(u1.x & 0xFFFF); a1 += bf2f(u1.x >> 16);
                a2 += bf2f(u1.y & 0xFFFF); a3 += bf2f(u1.y >> 16);
            }
            o.x = alpha * a0 + beta * xv.x;
            o.y = alpha * a1 + beta * xv.y;
            o.z = alpha * a2 + beta * xv.z;
            o.w = alpha * a3 + beta * xv.w;
        } else {
            o = xv;
        }
        *(float4*)(orow + col) = o;
    }
}

extern "C" void kernel_launch(void* const* d_in, const int* in_sizes, int n_in,
                              void* d_out, int out_size, void* d_ws, size_t ws_size,
                              hipStream_t stream) {
    const float* x   = (const float*)d_in[0];
    const float* gw1 = (const float*)d_in[1];
    const float* gb1 = (const float*)d_in[2];
    const float* gw2 = (const float*)d_in[3];
    const float* gb2 = (const float*)d_in[4];
    const float* pw  = (const float*)d_in[5];
    const float* pb  = (const float*)d_in[6];
    const float* prw = (const float*)d_in[7];
    const float* blend = (const float*)d_in[8];
    float* out = (float*)d_out;
    float* gate_out = out + (size_t)B_TOK * HDIM;

    char* w = (char*)d_ws;
    size_t o = 0;
    u16* xb      = (u16*)(w + o);   o += (size_t)B_TOK * HDIM * 2;
    u16* pathWT  = (u16*)(w + o);   o += (size_t)NPATH * HDIM * HDIM * 2;
    u16* projWT  = (u16*)(w + o);   o += (size_t)NPATH * HDIM * HDIM * 2;
    u16* w1hT    = (u16*)(w + o);   o += (size_t)HGATE * HDIM * 2;
    u16* w1lT    = (u16*)(w + o);   o += (size_t)HGATE * HDIM * 2;
    // hbuf (fp32, used until topk) overlaid with pcomp (bf16, written after topk)
    size_t uni = o;
    float* hbuf  = (float*)(w + uni);
    u16* pcomp   = (u16*)(w + uni);
    size_t hbuf_sz  = (size_t)B_TOK * HGATE * 4;
    size_t pcomp_sz = (size_t)MAXROWS * HDIM * 2;
    o += (hbuf_sz > pcomp_sz ? hbuf_sz : pcomp_sz);
    // xh/xl (f16 hi+residual of x, dead after gate GEMM) overlaid with hid (written by path1)
    size_t uni2 = o;
    u16* xh16    = (u16*)(w + uni2);                           // B_TOK*HDIM*2
    u16* xl16    = (u16*)(w + uni2 + (size_t)B_TOK * HDIM * 2); // B_TOK*HDIM*2
    u16* hid     = (u16*)(w + uni2);
    o += (size_t)MAXROWS * HDIM * 2;   // 69.2MB >= 2 * 33.6MB
    float* wnorm = (float*)(w + o); o += (size_t)B_TOK * NPATH * 4;
    int* tokens  = (int*)(w + o);   o += (size_t)NPATH * B_TOK * 4;
    uint32_t* slots = (uint32_t*)(w + o); o += (size_t)B_TOK * 2 * 4;
    int* counts  = (int*)(w + o);   o += 64;
    int* poffs   = (int*)(w + o);   o += 64;

    hipMemsetAsync(counts, 0, NPATH * sizeof(int), stream);
    k_convert_x<<<dim3((B_TOK * HDIM) / 1024), dim3(256), 0, stream>>>(x, xb, xh16, xl16);
    k_split_w1<<<dim3(HGATE / 32, HDIM / 32), dim3(32, 8), 0, stream>>>(gw1, w1hT, w1lT);
    k_transpose_bf16<<<dim3(32, 32, 8), dim3(32, 8), 0, stream>>>(pw, pathWT);
    k_transpose_bf16<<<dim3(32, 32, 8), dim3(32, 8), 0, stream>>>(prw, projWT);
    k_gate_mfma<<<dim3(HGATE / 128, B_TOK / 128), dim3(256), 0, stream>>>(
        xh16, xl16, w1hT, w1lT, gb1, hbuf);
    k_gate_topk<<<dim3(B_TOK / 64), dim3(256), 0, stream>>>(hbuf, gw2, gb2, gate_out,
                                                            wnorm, counts, tokens, slots);
    k_prefix<<<dim3(1), dim3(64), 0, stream>>>(counts, poffs);
    k_path1<<<dim3(8, 128, 8), dim3(256), 0, stream>>>(xb, pathWT, pb, hid,
                                                       counts, tokens, poffs);
    k_path2<<<dim3(8, 128, 8), dim3(256), 0, stream>>>(hid, projWT, wnorm, pcomp,
                                                       counts, tokens, poffs);
    k_blend2<<<dim3(B_TOK / 4), dim3(256), 0, stream>>>(x, pcomp, slots, poffs, blend, out);
}